// Round 1
// 1035.265 us; speedup vs baseline: 1.1120x; 1.1120x over previous
//
#include <hip/hip_runtime.h>
#include <hip/hip_bf16.h>
#include <math.h>

typedef __attribute__((ext_vector_type(8))) short short8;
typedef __attribute__((ext_vector_type(4))) float floatx4;

constexpr int kB  = 64;    // batch
constexpr int kP  = 50;    // nodes per graph
constexpr int kE  = 400;   // edges per graph
constexpr int kF1 = 128;   // GCN feature dim (2H)
constexpr int kH  = 64;    // H
constexpr int kNT = 2000;  // head output per sample
constexpr int kNEDGE = kE + kP;  // incl. self loops

__device__ __forceinline__ float leakyf(float v) { return v >= 0.f ? v : 0.01f * v; }

// packed f32x2 -> bf16x2 (RNE) -- compiles to v_cvt_pk_bf16_f32
__device__ __forceinline__ unsigned pk_bf2(float lo, float hi) {
    union { __hip_bfloat162 h; unsigned u; } cv;
    cv.h = __float22bfloat162_rn(make_float2(lo, hi));
    return cv.u;
}

// C_partial[z][Mblk][N] = A[M,K] @ W[K,N] (bf16 MFMA 16x16x32, fp32 acc).
// grid (N/64, M/64, splits), block 256, kchunk = K/splits (multiple of 64).
// Double-buffered LDS, register prefetch of tile t+1 issued before MFMAs of
// tile t, ONE barrier per 64-K step. No atomics: each z-slice writes its own
// partial; a fused reduce kernel sums them.
__global__ __launch_bounds__(256) void gemm_bf16(
    const float* __restrict__ A, const float* __restrict__ W, float* __restrict__ C,
    int N, int K, int kchunk)
{
    // stride 72 shorts (144 B): 16B-aligned b128 frags, bank step 4 -> 2-way
    // max on reads/writes (free per m136).
    __shared__ unsigned short lds_a[2][64 * 72];
    __shared__ unsigned short lds_w[2][64 * 72];

    const int t  = threadIdx.x;
    const int n0 = blockIdx.x * 64;
    const int m0 = blockIdx.y * 64;
    const int k0 = blockIdx.z * kchunk;
    const int nsteps = kchunk >> 6;

    const int ar = t >> 2;            // A stage: row 0..63
    const int ac = (t & 3) << 4;      // A stage: k offset 0/16/32/48
    const int wc = t & 63;            // W stage: col 0..63
    const int wk = (t >> 6) << 4;     // W stage: k offset 0/16/32/48

    const int wave = t >> 6;
    const int lane = t & 63;
    const int lrow = lane & 15;
    const int quad = lane >> 4;

    floatx4 acc[4];
#pragma unroll
    for (int c = 0; c < 4; ++c) acc[c] = (floatx4)0.f;

    const float* Ab = A + (size_t)(m0 + ar) * K + k0 + ac;
    const float* Wb = W + (size_t)(k0 + wk) * N + n0 + wc;

    float4 a_r[4];    // 16 floats of A (row ar, 16 consecutive k)
    float  w_r[16];   // 16 floats of W (col wc, 16 consecutive k)

    auto load_tile = [&](int st) {
        const float4* ap = reinterpret_cast<const float4*>(Ab + (size_t)st * 64);
#pragma unroll
        for (int i = 0; i < 4; ++i) a_r[i] = ap[i];
        const float* wp = Wb + (size_t)st * 64 * N;
#pragma unroll
        for (int i = 0; i < 16; ++i) w_r[i] = wp[(size_t)i * N];
    };
    auto stage = [&](int buf) {
        unsigned u[8];
#pragma unroll
        for (int i = 0; i < 4; ++i) {
            u[2 * i]     = pk_bf2(a_r[i].x, a_r[i].y);
            u[2 * i + 1] = pk_bf2(a_r[i].z, a_r[i].w);
        }
        uint4* da = reinterpret_cast<uint4*>(&lds_a[buf][ar * 72 + ac]);
        da[0] = make_uint4(u[0], u[1], u[2], u[3]);
        da[1] = make_uint4(u[4], u[5], u[6], u[7]);
#pragma unroll
        for (int i = 0; i < 8; ++i) u[i] = pk_bf2(w_r[2 * i], w_r[2 * i + 1]);
        uint4* dw = reinterpret_cast<uint4*>(&lds_w[buf][wc * 72 + wk]);
        dw[0] = make_uint4(u[0], u[1], u[2], u[3]);
        dw[1] = make_uint4(u[4], u[5], u[6], u[7]);
    };
    auto compute = [&](int buf) {
#pragma unroll
        for (int s = 0; s < 2; ++s) {
            short8 af = *reinterpret_cast<const short8*>(
                &lds_a[buf][(wave * 16 + lrow) * 72 + s * 32 + quad * 8]);
#pragma unroll
            for (int c = 0; c < 4; ++c) {
                short8 bf = *reinterpret_cast<const short8*>(
                    &lds_w[buf][(c * 16 + lrow) * 72 + s * 32 + quad * 8]);
                acc[c] = __builtin_amdgcn_mfma_f32_16x16x32_bf16(af, bf, acc[c], 0, 0, 0);
            }
        }
    };

    load_tile(0);
    stage(0);
    __syncthreads();

    for (int st = 0; st < nsteps; ++st) {
        const int cur = st & 1;
        if (st + 1 < nsteps) load_tile(st + 1);   // issue early: fly under MFMAs
        compute(cur);
        if (st + 1 < nsteps) stage(cur ^ 1);      // vmcnt wait lands here
        __syncthreads();                          // single barrier per step
    }

    // C/D layout: col = lane&15, row = quad*4 + reg  [verified m89/m91]
    float* Cp = C + (size_t)blockIdx.z * gridDim.y * 64 * N;
#pragma unroll
    for (int c = 0; c < 4; ++c)
#pragma unroll
        for (int r = 0; r < 4; ++r) {
            int row = m0 + wave * 16 + quad * 4 + r;
            int col = n0 + c * 16 + lrow;
            Cp[(size_t)row * N + col] = acc[c][r];
        }
}

// out = act(sum_z part[z] + bias), float4-vectorized. total4 = (64*N)/4.
__global__ __launch_bounds__(256) void reduce_bias_act(
    const float* __restrict__ part, const float* __restrict__ bias,
    float* __restrict__ out, int total4, int N4, int slices, int do_leaky)
{
    int i = blockIdx.x * 256 + threadIdx.x;
    if (i >= total4) return;
    const float4* p4 = reinterpret_cast<const float4*>(part);
    float4 s = p4[i];
    for (int z = 1; z < slices; ++z) {
        float4 p = p4[(size_t)z * total4 + i];
        s.x += p.x; s.y += p.y; s.z += p.z; s.w += p.w;
    }
    float4 b = reinterpret_cast<const float4*>(bias)[i % N4];
    s.x += b.x; s.y += b.y; s.z += b.z; s.w += b.w;
    if (do_leaky) { s.x = leakyf(s.x); s.y = leakyf(s.y); s.z = leakyf(s.z); s.w = leakyf(s.w); }
    reinterpret_cast<float4*>(out)[i] = s;
}

// Per-sample GCN aggregation, 2 blocks/sample (feature halves): 128 blocks.
__global__ __launch_bounds__(256) void gcn_agg(
    const float* __restrict__ hpre, const int* __restrict__ ei,
    const float* __restrict__ bias, float* __restrict__ out)
{
    __shared__ float s_agg[kP * 64];
    __shared__ float s_deg[kP];
    __shared__ float s_dinv[kP];
    __shared__ int   s_src[kNEDGE];
    __shared__ int   s_dst[kNEDGE];
    __shared__ float s_norm[kNEDGE];

    const int s    = blockIdx.x >> 1;
    const int half = blockIdx.x & 1;
    const int t    = threadIdx.x;

    for (int i = t; i < kP * 64; i += 256) s_agg[i] = 0.f;
    if (t < kP) s_deg[t] = 0.f;
    __syncthreads();

    for (int e = t; e < kE; e += 256) {
        int src = ei[(size_t)s * 2 * kE + e];
        int dst = ei[(size_t)s * 2 * kE + kE + e];
        s_src[e] = src; s_dst[e] = dst;
        atomicAdd(&s_deg[dst], 1.f);
    }
    if (t < kP) {          // self loops
        s_src[kE + t] = t; s_dst[kE + t] = t;
        atomicAdd(&s_deg[t], 1.f);
    }
    __syncthreads();
    if (t < kP) s_dinv[t] = rsqrtf(s_deg[t]);   // deg >= 1 (self loop)
    __syncthreads();
    for (int e = t; e < kNEDGE; e += 256)
        s_norm[e] = s_dinv[s_src[e]] * s_dinv[s_dst[e]];
    __syncthreads();

    const int f   = t & 63;
    const int sub = t >> 6;
    const float* hb = hpre + (size_t)s * kP * kF1 + half * 64 + f;
    for (int e = sub; e < kNEDGE; e += 4) {
        float v = hb[s_src[e] * kF1] * s_norm[e];
        atomicAdd(&s_agg[s_dst[e] * 64 + f], v);
    }
    __syncthreads();

    for (int i = t; i < kP * 64; i += 256) {
        int p = i >> 6, ff = i & 63;
        out[((size_t)s * kP + p) * kF1 + half * 64 + ff] =
            leakyf(s_agg[i] + bias[half * 64 + ff]);
    }
}

// Per-sample head: mean-pool -> leaky(Wf1) -> Wf2 -> cumsum(1000 x 2) -> sigmoid
__global__ __launch_bounds__(256) void head_k(
    const float* __restrict__ a2, const float* __restrict__ Wf1,
    const float* __restrict__ bf1, const float* __restrict__ Wf2,
    const float* __restrict__ bf2, float* __restrict__ out)
{
    __shared__ float s_pool[kF1];
    __shared__ float s_z[kH];
    __shared__ float s_t[kNT];
    __shared__ float ps0[256], ps1[256];

    const int s = blockIdx.x;
    const int t = threadIdx.x;

    if (t < kF1) {
        float acc = 0.f;
        for (int p = 0; p < kP; ++p)
            acc += a2[((size_t)s * kP + p) * kF1 + t];
        s_pool[t] = acc * (1.f / kP);
    }
    __syncthreads();
    if (t < kH) {
        float acc = bf1[t];
        for (int k = 0; k < kF1; ++k)
            acc += s_pool[k] * Wf1[k * kH + t];
        s_z[t] = leakyf(acc);
    }
    __syncthreads();
    for (int c = t; c < kNT; c += 256) {
        float acc = bf2[c];
        for (int k = 0; k < kH; ++k)
            acc += s_z[k] * Wf2[(size_t)k * kNT + c];
        s_t[c] = acc;
    }
    __syncthreads();

    // inclusive cumsum over 1000 rows, 2 independent chains
    float l0 = 0.f, l1 = 0.f;
    const int r0 = t * 4;
    if (r0 < 1000) {
#pragma unroll
        for (int i = 0; i < 4; ++i) {
            l0 += s_t[(r0 + i) * 2];
            l1 += s_t[(r0 + i) * 2 + 1];
        }
    }
    ps0[t] = l0; ps1[t] = l1;
    __syncthreads();
    for (int off = 1; off < 256; off <<= 1) {
        float v0 = (t >= off) ? ps0[t - off] : 0.f;
        float v1 = (t >= off) ? ps1[t - off] : 0.f;
        __syncthreads();
        ps0[t] += v0; ps1[t] += v1;
        __syncthreads();
    }
    if (r0 < 1000) {
        float run0 = ps0[t] - l0;   // exclusive prefix
        float run1 = ps1[t] - l1;
        #pragma unroll
        for (int i = 0; i < 4; ++i) {
            run0 += s_t[(r0 + i) * 2];
            run1 += s_t[(r0 + i) * 2 + 1];
            out[(size_t)s * kNT + (r0 + i) * 2]     = 1.f / (1.f + expf(-run0));
            out[(size_t)s * kNT + (r0 + i) * 2 + 1] = 1.f / (1.f + expf(-run1));
        }
    }
}

extern "C" void kernel_launch(void* const* d_in, const int* in_sizes, int n_in,
                              void* d_out, int out_size, void* d_ws, size_t ws_size,
                              hipStream_t stream)
{
    const float* x   = (const float*)d_in[0];   // b: (64, 25600)
    const int*   ei  = (const int*)d_in[1];     // (64, 2, 400)
    const float* W1  = (const float*)d_in[2];
    const float* b1  = (const float*)d_in[3];
    const float* W2  = (const float*)d_in[4];
    const float* b2  = (const float*)d_in[5];
    const float* W3  = (const float*)d_in[6];
    const float* b3  = (const float*)d_in[7];
    const float* Wc1 = (const float*)d_in[8];
    const float* bc1 = (const float*)d_in[9];
    const float* Wc2 = (const float*)d_in[10];
    const float* bc2 = (const float*)d_in[11];
    const float* Wf1 = (const float*)d_in[12];
    const float* bf1 = (const float*)d_in[13];
    const float* Wf2 = (const float*)d_in[14];
    const float* bf2 = (const float*)d_in[15];
    float* out = (float*)d_out;

    // workspace (floats): part reused across the 3 encoder GEMMs.
    // max(16*204800, 5*409600, 4*819200) = 3,276,800. total = 6,348,800 fl = 25.4 MB
    float* part  = (float*)d_ws;
    float* h1    = part + 3276800;     // 64*3200
    float* h2    = h1 + 204800;        // 64*6400
    float* nodes = h2 + 409600;        // 64*12800
    float* g1    = nodes + 819200;     // 3200*128
    float* a1    = g1 + 409600;
    float* g2    = a1 + 409600;
    float* a2    = g2 + 409600;

    // encoder: x(64,25600) -> h1(64,3200) -> h2(64,6400) -> nodes(64,12800)
    gemm_bf16<<<dim3(50, 1, 16), 256, 0, stream>>>(x,  W1, part, 3200, 25600, 1600);
    reduce_bias_act<<<200, 256, 0, stream>>>(part, b1, h1,     51200,  800, 16, 1);
    gemm_bf16<<<dim3(100, 1, 5), 256, 0, stream>>>(h1, W2, part, 6400, 3200, 640);
    reduce_bias_act<<<400, 256, 0, stream>>>(part, b2, h2,    102400, 1600,  5, 1);
    gemm_bf16<<<dim3(200, 1, 4), 256, 0, stream>>>(h2, W3, part, 12800, 6400, 1600);
    reduce_bias_act<<<800, 256, 0, stream>>>(part, b3, nodes, 204800, 3200,  4, 0);

    // GCN (batched GEMM across samples + per-sample aggregation)
    gemm_bf16<<<dim3(2, 50, 1), 256, 0, stream>>>(nodes, Wc1, g1, 128, 256, 256);
    gcn_agg<<<128, 256, 0, stream>>>(g1, ei, bc1, a1);
    gemm_bf16<<<dim3(2, 50, 1), 256, 0, stream>>>(a1, Wc2, g2, 128, 128, 128);
    gcn_agg<<<128, 256, 0, stream>>>(g2, ei, bc2, a2);

    // head + cumsum + sigmoid
    head_k<<<64, 256, 0, stream>>>(a2, Wf1, bf1, Wf2, bf2, out);
}